// Round 2
// baseline (190.118 us; speedup 1.0000x reference)
//
#include <hip/hip_runtime.h>
#include <stdint.h>

typedef __attribute__((ext_vector_type(8))) short short8;
typedef __attribute__((ext_vector_type(4))) float f32x4;

#define NEG_INF (-__builtin_inff())

// Problem constants
#define B_ROWS 2048
#define N_KEYS 65536
#define DIM    128

// ws layout (fast path):
//   ki:   512 tiles * 2048 short8  = 16 MB   (keys, bf16, tile-fragment order)
//   xi:    16 tiles * 2048 short8  = 0.5 MB  (x,    bf16, tile-fragment order)
//   cmax: 2048 * 1024 floats       = 8  MB   (per-row per-64-key-chunk masked max)

__device__ __forceinline__ unsigned short f2bf(float f) {
  unsigned u = __float_as_uint(f);
  u = (u + 0x7FFFu + ((u >> 16) & 1u)) >> 16;  // RNE
  return (unsigned short)u;
}

// Tile image layout: for a 128-row x 128-col(bf16 K) tile, 16B chunk index
//   li = (row_local>>4)*256 + kchunk*16 + (row_local&15),  kchunk = k/8 in 0..15
// so a lane-l ds_read_b128 at chunk (row_blk*256 + kk*64 + l) yields the
// MFMA 16x16x32 operand fragment: row = l&15, k = kk*32 + (l>>4)*8 + e.
__global__ __launch_bounds__(256) void convert_kernel(
    const float* __restrict__ x, const float* __restrict__ keys,
    short8* __restrict__ xi, short8* __restrict__ ki) {
  int t = blockIdx.x * 256 + threadIdx.x;
  const float* src;
  short8* dst;
  if (t < N_KEYS * 16) {
    int n = t >> 4, c = t & 15;
    src = keys + (size_t)n * DIM + c * 8;
    int tile = n >> 7, rl = n & 127;
    dst = ki + (size_t)tile * 2048 + ((rl >> 4) * 256 + c * 16 + (rl & 15));
  } else {
    t -= N_KEYS * 16;
    if (t >= B_ROWS * 16) return;
    int n = t >> 4, c = t & 15;
    src = x + (size_t)n * DIM + c * 8;
    int tile = n >> 7, rl = n & 127;
    dst = xi + (size_t)tile * 2048 + ((rl >> 4) * 256 + c * 16 + (rl & 15));
  }
  f32x4 v0 = *(const f32x4*)(src);
  f32x4 v1 = *(const f32x4*)(src + 4);
  short8 o;
  o[0] = (short)f2bf(v0[0]); o[1] = (short)f2bf(v0[1]);
  o[2] = (short)f2bf(v0[2]); o[3] = (short)f2bf(v0[3]);
  o[4] = (short)f2bf(v1[0]); o[5] = (short)f2bf(v1[1]);
  o[6] = (short)f2bf(v1[2]); o[7] = (short)f2bf(v1[3]);
  *dst = o;
}

#define GLDS(gp, lp)                                                      \
  __builtin_amdgcn_global_load_lds(                                       \
      (const __attribute__((address_space(1))) void*)(gp),                \
      (__attribute__((address_space(3))) void*)(lp), 16, 0, 0)

// 128x128 tile, 4 waves in 2x2. Whole K=128 resident. Writes masked per-row
// max over each 64-key chunk: cmax[row][ntile*2 + wc].
__global__ __launch_bounds__(256, 2) void sim_kernel(
    const short8* __restrict__ xi, const short8* __restrict__ ki,
    const int* __restrict__ act, float* __restrict__ cmax) {
  __shared__ short8 As[2048];   // 32 KB
  __shared__ short8 Bs[2048];   // 32 KB
  __shared__ float actm[128];
  const int tid = threadIdx.x;
  const int w = tid >> 6, l = tid & 63;
  const int ntile = blockIdx.x, btile = blockIdx.y;

  const short8* ag = xi + (size_t)btile * 2048 + w * 512 + l;  // per-lane src
  const short8* bg = ki + (size_t)ntile * 2048 + w * 512 + l;
#pragma unroll
  for (int i = 0; i < 8; i++) {
    GLDS(ag + i * 64, As + w * 512 + i * 64);  // LDS dest wave-uniform
    GLDS(bg + i * 64, Bs + w * 512 + i * 64);
  }
  if (tid < 128) {
    int a = act[ntile * 128 + tid];
    actm[tid] = a ? 0.0f : NEG_INF;
  }
  __syncthreads();  // drains vmcnt for global_load_lds

  const int wr = w >> 1, wc = w & 1;
  f32x4 acc[4][4];
#pragma unroll
  for (int mi = 0; mi < 4; mi++)
#pragma unroll
    for (int ni = 0; ni < 4; ni++) acc[mi][ni] = f32x4{0.f, 0.f, 0.f, 0.f};

#pragma unroll
  for (int kk = 0; kk < 4; kk++) {
    short8 af[4], bf[4];
#pragma unroll
    for (int mi = 0; mi < 4; mi++) af[mi] = As[(wr * 4 + mi) * 256 + kk * 64 + l];
#pragma unroll
    for (int ni = 0; ni < 4; ni++) bf[ni] = Bs[(wc * 4 + ni) * 256 + kk * 64 + l];
#pragma unroll
    for (int mi = 0; mi < 4; mi++)
#pragma unroll
      for (int ni = 0; ni < 4; ni++)
        acc[mi][ni] = __builtin_amdgcn_mfma_f32_16x16x32_bf16(
            af[mi], bf[ni], acc[mi][ni], 0, 0, 0);
  }

  // Epilogue: masked row-max over this wave's 64 cols.
  // C layout (verified m89/m91): col = lane&15, row = (lane>>4)*4 + reg.
  const int lg = l >> 4, lr = l & 15;
#pragma unroll
  for (int mi = 0; mi < 4; mi++) {
    float rm[4];
#pragma unroll
    for (int r = 0; r < 4; r++) rm[r] = NEG_INF;
#pragma unroll
    for (int ni = 0; ni < 4; ni++) {
      float m = actm[wc * 64 + ni * 16 + lr];
#pragma unroll
      for (int r = 0; r < 4; r++) rm[r] = fmaxf(rm[r], acc[mi][ni][r] + m);
    }
#pragma unroll
    for (int r = 0; r < 4; r++) {
      float v = rm[r];
      v = fmaxf(v, __shfl_xor(v, 1));
      v = fmaxf(v, __shfl_xor(v, 2));
      v = fmaxf(v, __shfl_xor(v, 4));
      v = fmaxf(v, __shfl_xor(v, 8));
      rm[r] = v;
    }
    if (lr == 0) {
      int rowbase = btile * 128 + wr * 64 + mi * 16 + lg * 4;
      int chunk = ntile * 2 + wc;
#pragma unroll
      for (int r = 0; r < 4; r++)
        cmax[(size_t)(rowbase + r) * 1024 + chunk] = rm[r];
    }
  }
}

// One block per row: reduce 1024 chunk maxima, fp64-rescore candidate chunks
// (margin 0.75 >> hard bf16 rounding bound ~0.27), exact argmax w/ first-index
// tie-break, write outputs.
__global__ __launch_bounds__(256) void finalize_kernel(
    const float* __restrict__ x, const float* __restrict__ keys,
    const float* __restrict__ vals, const int* __restrict__ act,
    const float* __restrict__ cmax, float* __restrict__ out) {
  __shared__ float xr[128];
  __shared__ float wred[4];
  __shared__ int cand[64];
  __shared__ int ncand;
  __shared__ int bestn_s;
  __shared__ float skeys[64 * 129];  // padded: stride 129 -> conflict-free rows
  const int b = blockIdx.x, tid = threadIdx.x;
  if (tid < 128) xr[tid] = x[(size_t)b * 128 + tid];
  if (tid == 0) ncand = 0;
  __syncthreads();

  const float* cm = cmax + (size_t)b * 1024;
  float c0 = cm[tid], c1 = cm[tid + 256], c2 = cm[tid + 512], c3 = cm[tid + 768];
  float lm = fmaxf(fmaxf(c0, c1), fmaxf(c2, c3));
#pragma unroll
  for (int s = 1; s < 64; s <<= 1) lm = fmaxf(lm, __shfl_xor(lm, s));
  if ((tid & 63) == 0) wred[tid >> 6] = lm;
  __syncthreads();
  float M = fmaxf(fmaxf(wred[0], wred[1]), fmaxf(wred[2], wred[3]));
  float thr = M - 0.75f;

  if (c0 > thr) { int p = atomicAdd(&ncand, 1); if (p < 64) cand[p] = tid; }
  if (c1 > thr) { int p = atomicAdd(&ncand, 1); if (p < 64) cand[p] = tid + 256; }
  if (c2 > thr) { int p = atomicAdd(&ncand, 1); if (p < 64) cand[p] = tid + 512; }
  if (c3 > thr) { int p = atomicAdd(&ncand, 1); if (p < 64) cand[p] = tid + 768; }
  __syncthreads();
  int nc = ncand; if (nc > 64) nc = 64;

  double bv = -(double)__builtin_inf();
  int bn = 0x7FFFFFFF;
  for (int ci = 0; ci < nc; ci++) {
    int cch = cand[ci];
    const float* kbase = keys + (size_t)cch * 64 * 128;
#pragma unroll
    for (int i = 0; i < 32; i++) {
      int idx = tid + i * 256;
      skeys[(idx >> 7) * 129 + (idx & 127)] = kbase[idx];
    }
    __syncthreads();
    if (tid < 64) {
      int n = cch * 64 + tid;
      if (act[n] != 0) {
        const float* kr = skeys + tid * 129;
        double s = 0.0;
#pragma unroll
        for (int d = 0; d < 128; d++) s += (double)xr[d] * (double)kr[d];
        if (s > bv || (s == bv && n < bn)) { bv = s; bn = n; }
      }
    }
    __syncthreads();
  }

  if (tid < 64) {
#pragma unroll
    for (int s = 1; s < 64; s <<= 1) {
      double ov = __shfl_xor(bv, s);
      int on = __shfl_xor(bn, s);
      if (ov > bv || (ov == bv && on < bn)) { bv = ov; bn = on; }
    }
    if (tid == 0) {
      bestn_s = bn;
      out[262144 + b] = (float)bv;       // confidence
      out[264192 + b] = (float)bn;       // best_match_idx (float-encoded)
    }
  }
  __syncthreads();
  int n = bestn_s;
  if (tid < 128) out[(size_t)b * 128 + tid] = vals[(size_t)n * 128 + tid];
}

// ---------- ws-free fallback (only if ws_size too small): exact fp64 ----------
// 8 rows per block; every thread strides over keys; exact argmax.
__global__ __launch_bounds__(256) void direct_kernel(
    const float* __restrict__ x, const float* __restrict__ keys,
    const float* __restrict__ vals, const int* __restrict__ act,
    float* __restrict__ out) {
  __shared__ float xr[8][128];
  __shared__ double redv[8][4];
  __shared__ int redn[8][4];
  __shared__ int bests[8];
  const int tid = threadIdx.x;
  const int r0 = blockIdx.x * 8;
  const int w = tid >> 6, l = tid & 63;
#pragma unroll
  for (int i = 0; i < 4; i++) {
    int idx = tid + i * 256;                       // 1024 floats
    xr[idx >> 7][idx & 127] = x[(size_t)(r0 + (idx >> 7)) * 128 + (idx & 127)];
  }
  __syncthreads();

  double bv[8];
  int bn[8];
#pragma unroll
  for (int r = 0; r < 8; r++) { bv[r] = -(double)__builtin_inf(); bn[r] = 0x7FFFFFFF; }

  for (int n = tid; n < N_KEYS; n += 256) {
    if (act[n] == 0) continue;
    const float* kr = keys + (size_t)n * 128;
    double s[8];
#pragma unroll
    for (int r = 0; r < 8; r++) s[r] = 0.0;
    for (int d = 0; d < 128; d += 4) {
      f32x4 kv = *(const f32x4*)(kr + d);
#pragma unroll
      for (int r = 0; r < 8; r++) {
        s[r] += (double)xr[r][d] * (double)kv[0];
        s[r] += (double)xr[r][d + 1] * (double)kv[1];
        s[r] += (double)xr[r][d + 2] * (double)kv[2];
        s[r] += (double)xr[r][d + 3] * (double)kv[3];
      }
    }
#pragma unroll
    for (int r = 0; r < 8; r++)
      if (s[r] > bv[r]) { bv[r] = s[r]; bn[r] = n; }  // n strictly increasing per thread
  }

#pragma unroll
  for (int r = 0; r < 8; r++) {
    double v = bv[r]; int n = bn[r];
#pragma unroll
    for (int s = 1; s < 64; s <<= 1) {
      double ov = __shfl_xor(v, s);
      int on = __shfl_xor(n, s);
      if (ov > v || (ov == v && on < n)) { v = ov; n = on; }
    }
    if (l == 0) { redv[r][w] = v; redn[r][w] = n; }
  }
  __syncthreads();
  if (tid < 8) {
    double v = redv[tid][0]; int n = redn[tid][0];
#pragma unroll
    for (int j = 1; j < 4; j++) {
      double ov = redv[tid][j]; int on = redn[tid][j];
      if (ov > v || (ov == v && on < n)) { v = ov; n = on; }
    }
    bests[tid] = n;
    out[262144 + r0 + tid] = (float)v;
    out[264192 + r0 + tid] = (float)n;
  }
  __syncthreads();
#pragma unroll
  for (int i = 0; i < 4; i++) {
    int idx = tid + i * 256;
    int r = idx >> 7, d = idx & 127;
    out[(size_t)(r0 + r) * 128 + d] = vals[(size_t)bests[r] * 128 + d];
  }
}

extern "C" void kernel_launch(void* const* d_in, const int* in_sizes, int n_in,
                              void* d_out, int out_size, void* d_ws, size_t ws_size,
                              hipStream_t stream) {
  const float* x    = (const float*)d_in[0];
  const float* keys = (const float*)d_in[1];
  const float* vals = (const float*)d_in[2];
  const int*   act  = (const int*)d_in[3];
  float* out = (float*)d_out;

  const size_t need = (size_t)(512 * 2048 + 16 * 2048) * sizeof(short8) +
                      (size_t)2048 * 1024 * sizeof(float);
  if (ws_size >= need) {
    short8* ki   = (short8*)d_ws;
    short8* xi   = ki + 512 * 2048;
    float*  cmax = (float*)(xi + 16 * 2048);
    convert_kernel<<<4224, 256, 0, stream>>>(x, keys, xi, ki);
    sim_kernel<<<dim3(512, 16), 256, 0, stream>>>(xi, ki, act, cmax);
    finalize_kernel<<<2048, 256, 0, stream>>>(x, keys, vals, act, cmax, out);
  } else {
    direct_kernel<<<256, 256, 0, stream>>>(x, keys, vals, act, out);
  }
}

// Round 3
// 181.628 us; speedup vs baseline: 1.0467x; 1.0467x over previous
//
#include <hip/hip_runtime.h>
#include <stdint.h>

typedef __attribute__((ext_vector_type(8))) short short8;
typedef __attribute__((ext_vector_type(4))) float f32x4;

#define NEG_INF (-__builtin_inff())

// Problem constants
#define B_ROWS 2048
#define N_KEYS 65536
#define DIM    128

// ws layout (fast path):
//   xi:    16 tiles * 2048 short8      = 512 KB (x, bf16, tile-fragment order)
//   cmaxT: 1024 chunks * 2048 rows f32 = 8 MB   (per-64-key-chunk masked max, TRANSPOSED)

__device__ __forceinline__ unsigned short f2bf(float f) {
  unsigned u = __float_as_uint(f);
  u = (u + 0x7FFFu + ((u >> 16) & 1u)) >> 16;  // RNE
  return (unsigned short)u;
}

// Tile image layout (16B chunks): li = (rl>>4)*256 + c*16 + (rl&15), c = k/8.
// Lane-l ds_read_b128 at chunk (rowblk*256 + kk*64 + l) yields the MFMA
// 16x16x32 operand fragment: row = l&15, k = kk*32 + (l>>4)*8 + e.

// x f32 -> xi bf16 fragment image. Thread per DST chunk (linear coalesced
// writes); scattered reads are L2-absorbed (x is 1 MB).
__global__ __launch_bounds__(256) void convert_x_kernel(
    const float* __restrict__ x, short8* __restrict__ xi) {
  int t = blockIdx.x * 256 + threadIdx.x;      // 32768 chunks
  int tile = t >> 11, loc = t & 2047;
  int rl = ((loc >> 8) << 4) + (loc & 15);
  int c = (loc >> 4) & 15;
  const float* src = x + (size_t)(tile * 128 + rl) * DIM + c * 8;
  f32x4 v0 = *(const f32x4*)(src);
  f32x4 v1 = *(const f32x4*)(src + 4);
  short8 o;
  o[0] = (short)f2bf(v0[0]); o[1] = (short)f2bf(v0[1]);
  o[2] = (short)f2bf(v0[2]); o[3] = (short)f2bf(v0[3]);
  o[4] = (short)f2bf(v1[0]); o[5] = (short)f2bf(v1[1]);
  o[6] = (short)f2bf(v1[2]); o[7] = (short)f2bf(v1[3]);
  xi[t] = o;
}

#define GLDS(gp, lp)                                                      \
  __builtin_amdgcn_global_load_lds(                                       \
      (const __attribute__((address_space(1))) void*)(gp),                \
      (__attribute__((address_space(3))) void*)(lp), 16, 0, 0)

// One block per 128-key tile. Stage+convert keys f32->bf16 image ONCE, then
// loop all 16 x-tiles (A re-staged per btile via global_load_lds from xi).
// Writes masked per-row max per 64-key chunk: cmaxT[ntile*2+wc][row].
__global__ __launch_bounds__(256, 2) void sim2_kernel(
    const short8* __restrict__ xi, const float* __restrict__ keys,
    const int* __restrict__ act, float* __restrict__ cmaxT) {
  __shared__ short8 Bs[2048];   // 32 KB (keys tile, resident all iterations)
  __shared__ short8 As[2048];   // 32 KB (x tile, re-staged per btile)
  __shared__ float actm[128];
  const int tid = threadIdx.x;
  const int w = tid >> 6, l = tid & 63;
  const int ntile = blockIdx.x;

  // --- Stage + convert B tile: thread per dst chunk (linear ds_write) ---
  const float* kb = keys + (size_t)ntile * (128 * DIM);
#pragma unroll
  for (int it = 0; it < 8; ++it) {
    int li = it * 256 + tid;
    int rl = ((li >> 8) << 4) + (li & 15);
    int c = (li >> 4) & 15;
    const float* src = kb + rl * DIM + c * 8;
    f32x4 v0 = *(const f32x4*)(src);
    f32x4 v1 = *(const f32x4*)(src + 4);
    short8 o;
    o[0] = (short)f2bf(v0[0]); o[1] = (short)f2bf(v0[1]);
    o[2] = (short)f2bf(v0[2]); o[3] = (short)f2bf(v0[3]);
    o[4] = (short)f2bf(v1[0]); o[5] = (short)f2bf(v1[1]);
    o[6] = (short)f2bf(v1[2]); o[7] = (short)f2bf(v1[3]);
    Bs[li] = o;
  }
  if (tid < 128) {
    actm[tid] = act[ntile * 128 + tid] ? 0.0f : NEG_INF;
  }

  const int wr = w >> 1, wc = w & 1;
  const int lg = l >> 4, lr = l & 15;
  const short8* ag0 = xi + w * 512 + l;
  float* cout = cmaxT + (size_t)(ntile * 2 + wc) * B_ROWS;

  for (int bt = 0; bt < 16; ++bt) {
    __syncthreads();  // prev iter's As reads done (and Bs writes visible, bt=0)
    const short8* ag = ag0 + (size_t)bt * 2048;
#pragma unroll
    for (int i = 0; i < 8; i++)
      GLDS(ag + i * 64, As + w * 512 + i * 64);  // LDS dest wave-uniform+lane-linear
    __syncthreads();  // drains vmcnt -> As ready

    f32x4 acc[4][4];
#pragma unroll
    for (int mi = 0; mi < 4; mi++)
#pragma unroll
      for (int ni = 0; ni < 4; ni++) acc[mi][ni] = f32x4{0.f, 0.f, 0.f, 0.f};

#pragma unroll
    for (int kk = 0; kk < 4; kk++) {
      short8 af[4], bfv[4];
#pragma unroll
      for (int mi = 0; mi < 4; mi++) af[mi] = As[(wr * 4 + mi) * 256 + kk * 64 + l];
#pragma unroll
      for (int ni = 0; ni < 4; ni++) bfv[ni] = Bs[(wc * 4 + ni) * 256 + kk * 64 + l];
#pragma unroll
      for (int mi = 0; mi < 4; mi++)
#pragma unroll
        for (int ni = 0; ni < 4; ni++)
          acc[mi][ni] = __builtin_amdgcn_mfma_f32_16x16x32_bf16(
              af[mi], bfv[ni], acc[mi][ni], 0, 0, 0);
    }

    // Epilogue: masked row-max over this wave's 64 key-cols.
    // C layout (verified): col = lane&15, row = (lane>>4)*4 + reg.
#pragma unroll
    for (int mi = 0; mi < 4; mi++) {
      float rm[4];
#pragma unroll
      for (int r = 0; r < 4; r++) rm[r] = NEG_INF;
#pragma unroll
      for (int ni = 0; ni < 4; ni++) {
        float m = actm[wc * 64 + ni * 16 + lr];
#pragma unroll
        for (int r = 0; r < 4; r++) rm[r] = fmaxf(rm[r], acc[mi][ni][r] + m);
      }
#pragma unroll
      for (int r = 0; r < 4; r++) {
        float v = rm[r];
        v = fmaxf(v, __shfl_xor(v, 1));
        v = fmaxf(v, __shfl_xor(v, 2));
        v = fmaxf(v, __shfl_xor(v, 4));
        v = fmaxf(v, __shfl_xor(v, 8));
        rm[r] = v;
      }
      if (lr == 0) {  // lanes lg=0..3: 4 x f32x4 = 64B contiguous per mi
        int row = bt * 128 + wr * 64 + mi * 16 + lg * 4;
        *(f32x4*)(cout + row) = f32x4{rm[0], rm[1], rm[2], rm[3]};
      }
    }
  }
}

// One block per row: reduce 1024 chunk maxima (strided gather from cmaxT,
// L2/L3-absorbed), fp64-rescore candidate chunks (margin 0.75 >> bf16 bound
// ~0.21), exact argmax w/ first-index tie-break, write outputs.
__global__ __launch_bounds__(256) void finalize_kernel(
    const float* __restrict__ x, const float* __restrict__ keys,
    const float* __restrict__ vals, const int* __restrict__ act,
    const float* __restrict__ cmaxT, float* __restrict__ out) {
  __shared__ float xr[128];
  __shared__ float wred[4];
  __shared__ int cand[64];
  __shared__ int ncand;
  __shared__ int bestn_s;
  __shared__ float skeys[64 * 129];  // padded rows -> conflict-free
  const int b = blockIdx.x, tid = threadIdx.x;
  if (tid < 128) xr[tid] = x[(size_t)b * 128 + tid];
  if (tid == 0) ncand = 0;
  __syncthreads();

  const float* cm = cmaxT + b;  // cm[c*2048] = chunk c's max for this row
  float c0 = cm[(size_t)tid * B_ROWS];
  float c1 = cm[(size_t)(tid + 256) * B_ROWS];
  float c2 = cm[(size_t)(tid + 512) * B_ROWS];
  float c3 = cm[(size_t)(tid + 768) * B_ROWS];
  float lm = fmaxf(fmaxf(c0, c1), fmaxf(c2, c3));
#pragma unroll
  for (int s = 1; s < 64; s <<= 1) lm = fmaxf(lm, __shfl_xor(lm, s));
  if ((tid & 63) == 0) wred[tid >> 6] = lm;
  __syncthreads();
  float M = fmaxf(fmaxf(wred[0], wred[1]), fmaxf(wred[2], wred[3]));
  float thr = M - 0.75f;

  if (c0 > thr) { int p = atomicAdd(&ncand, 1); if (p < 64) cand[p] = tid; }
  if (c1 > thr) { int p = atomicAdd(&ncand, 1); if (p < 64) cand[p] = tid + 256; }
  if (c2 > thr) { int p = atomicAdd(&ncand, 1); if (p < 64) cand[p] = tid + 512; }
  if (c3 > thr) { int p = atomicAdd(&ncand, 1); if (p < 64) cand[p] = tid + 768; }
  __syncthreads();
  int nc = ncand; if (nc > 64) nc = 64;

  double bv = -(double)__builtin_inf();
  int bn = 0x7FFFFFFF;
  for (int ci = 0; ci < nc; ci++) {
    int cch = cand[ci];
    const float* kbase = keys + (size_t)cch * 64 * 128;
#pragma unroll
    for (int i = 0; i < 32; i++) {
      int idx = tid + i * 256;
      skeys[(idx >> 7) * 129 + (idx & 127)] = kbase[idx];
    }
    __syncthreads();
    if (tid < 64) {
      int n = cch * 64 + tid;
      if (act[n] != 0) {
        const float* kr = skeys + tid * 129;
        double s = 0.0;
#pragma unroll
        for (int d = 0; d < 128; d++) s += (double)xr[d] * (double)kr[d];
        if (s > bv || (s == bv && n < bn)) { bv = s; bn = n; }
      }
    }
    __syncthreads();
  }

  if (tid < 64) {
#pragma unroll
    for (int s = 1; s < 64; s <<= 1) {
      double ov = __shfl_xor(bv, s);
      int on = __shfl_xor(bn, s);
      if (ov > bv || (ov == bv && on < bn)) { bv = ov; bn = on; }
    }
    if (tid == 0) {
      bestn_s = bn;
      out[262144 + b] = (float)bv;       // confidence
      out[264192 + b] = (float)bn;       // best_match_idx (float-encoded)
    }
  }
  __syncthreads();
  int n = bestn_s;
  if (tid < 128) out[(size_t)b * 128 + tid] = vals[(size_t)n * 128 + tid];
}

// ---------- ws-free fallback (only if ws_size too small): exact fp64 ----------
__global__ __launch_bounds__(256) void direct_kernel(
    const float* __restrict__ x, const float* __restrict__ keys,
    const float* __restrict__ vals, const int* __restrict__ act,
    float* __restrict__ out) {
  __shared__ float xr[8][128];
  __shared__ double redv[8][4];
  __shared__ int redn[8][4];
  __shared__ int bests[8];
  const int tid = threadIdx.x;
  const int r0 = blockIdx.x * 8;
  const int w = tid >> 6, l = tid & 63;
#pragma unroll
  for (int i = 0; i < 4; i++) {
    int idx = tid + i * 256;
    xr[idx >> 7][idx & 127] = x[(size_t)(r0 + (idx >> 7)) * 128 + (idx & 127)];
  }
  __syncthreads();

  double bv[8];
  int bn[8];
#pragma unroll
  for (int r = 0; r < 8; r++) { bv[r] = -(double)__builtin_inf(); bn[r] = 0x7FFFFFFF; }

  for (int n = tid; n < N_KEYS; n += 256) {
    if (act[n] == 0) continue;
    const float* kr = keys + (size_t)n * 128;
    double s[8];
#pragma unroll
    for (int r = 0; r < 8; r++) s[r] = 0.0;
    for (int d = 0; d < 128; d += 4) {
      f32x4 kv = *(const f32x4*)(kr + d);
#pragma unroll
      for (int r = 0; r < 8; r++) {
        s[r] += (double)xr[r][d] * (double)kv[0];
        s[r] += (double)xr[r][d + 1] * (double)kv[1];
        s[r] += (double)xr[r][d + 2] * (double)kv[2];
        s[r] += (double)xr[r][d + 3] * (double)kv[3];
      }
    }
#pragma unroll
    for (int r = 0; r < 8; r++)
      if (s[r] > bv[r]) { bv[r] = s[r]; bn[r] = n; }
  }

#pragma unroll
  for (int r = 0; r < 8; r++) {
    double v = bv[r]; int n = bn[r];
#pragma unroll
    for (int s = 1; s < 64; s <<= 1) {
      double ov = __shfl_xor(v, s);
      int on = __shfl_xor(n, s);
      if (ov > v || (ov == v && on < n)) { v = ov; n = on; }
    }
    if (l == 0) { redv[r][w] = v; redn[r][w] = n; }
  }
  __syncthreads();
  if (tid < 8) {
    double v = redv[tid][0]; int n = redn[tid][0];
#pragma unroll
    for (int j = 1; j < 4; j++) {
      double ov = redv[tid][j]; int on = redn[tid][j];
      if (ov > v || (ov == v && on < n)) { v = ov; n = on; }
    }
    bests[tid] = n;
    out[262144 + r0 + tid] = (float)v;
    out[264192 + r0 + tid] = (float)n;
  }
  __syncthreads();
#pragma unroll
  for (int i = 0; i < 4; i++) {
    int idx = tid + i * 256;
    int r = idx >> 7, d = idx & 127;
    out[(size_t)(r0 + r) * 128 + d] = vals[(size_t)bests[r] * 128 + d];
  }
}

extern "C" void kernel_launch(void* const* d_in, const int* in_sizes, int n_in,
                              void* d_out, int out_size, void* d_ws, size_t ws_size,
                              hipStream_t stream) {
  const float* x    = (const float*)d_in[0];
  const float* keys = (const float*)d_in[1];
  const float* vals = (const float*)d_in[2];
  const int*   act  = (const int*)d_in[3];
  float* out = (float*)d_out;

  const size_t need = (size_t)16 * 2048 * sizeof(short8) +
                      (size_t)1024 * B_ROWS * sizeof(float);
  if (ws_size >= need) {
    short8* xi    = (short8*)d_ws;
    float*  cmaxT = (float*)(xi + 16 * 2048);
    convert_x_kernel<<<128, 256, 0, stream>>>(x, xi);
    sim2_kernel<<<512, 256, 0, stream>>>(xi, keys, act, cmaxT);
    finalize_kernel<<<2048, 256, 0, stream>>>(x, keys, vals, act, cmaxT, out);
  } else {
    direct_kernel<<<256, 256, 0, stream>>>(x, keys, vals, act, out);
  }
}

// Round 4
// 178.169 us; speedup vs baseline: 1.0671x; 1.0194x over previous
//
#include <hip/hip_runtime.h>
#include <stdint.h>

typedef __attribute__((ext_vector_type(8))) short short8;
typedef __attribute__((ext_vector_type(4))) float f32x4;

#define NEG_INF (-__builtin_inff())

// Problem constants
#define B_ROWS 2048
#define N_KEYS 65536
#define DIM    128

// ws layout (fast path):
//   xi:   16 tiles * 2048 short8  = 512 KB (x, bf16, tile-fragment order)
//   cmax: 2048 rows * 1024 chunks = 8 MB   (per-row per-64-key-chunk max)

__device__ __forceinline__ unsigned short f2bf(float f) {
  unsigned u = __float_as_uint(f);
  u = (u + 0x7FFFu + ((u >> 16) & 1u)) >> 16;  // RNE
  return (unsigned short)u;
}

// Tile image layout (16B chunks): li = (rl>>4)*256 + c*16 + (rl&15), c = k/8.
// Lane-l read at chunk (rowblk*256 + kk*64 + l) yields the MFMA 16x16x32
// operand fragment: row = l&15, k = kk*32 + (l>>4)*8 + e.  [verified r2/r3]

// x f32 -> xi bf16 fragment image. Thread per DST chunk (linear coalesced
// writes); scattered reads are L2-absorbed (x is 1 MB).
__global__ __launch_bounds__(256) void convert_x_kernel(
    const float* __restrict__ x, short8* __restrict__ xi) {
  int t = blockIdx.x * 256 + threadIdx.x;      // 32768 chunks
  int tile = t >> 11, loc = t & 2047;
  int rl = ((loc >> 8) << 4) + (loc & 15);
  int c = (loc >> 4) & 15;
  const float* src = x + (size_t)(tile * 128 + rl) * DIM + c * 8;
  f32x4 v0 = *(const f32x4*)(src);
  f32x4 v1 = *(const f32x4*)(src + 4);
  short8 o;
  o[0] = (short)f2bf(v0[0]); o[1] = (short)f2bf(v0[1]);
  o[2] = (short)f2bf(v0[2]); o[3] = (short)f2bf(v0[3]);
  o[4] = (short)f2bf(v1[0]); o[5] = (short)f2bf(v1[1]);
  o[6] = (short)f2bf(v1[2]); o[7] = (short)f2bf(v1[3]);
  xi[t] = o;
}

// One block per 128-key tile. Stage+convert+MASK keys f32->bf16 image in LDS
// once, lift B fragments to registers, then a BARRIER-FREE loop over all 16
// x-tiles reading A fragments straight from global xi (L2-resident).
// Inactive keys are zeroed (scores ~0 << row max ~43, filtered in finalize).
__global__ __launch_bounds__(256, 2) void sim3_kernel(
    const short8* __restrict__ xi, const float* __restrict__ keys,
    const int* __restrict__ act, float* __restrict__ cmax) {
  __shared__ short8 Bs[2048];   // 32 KB, used only during stage
  const int tid = threadIdx.x;
  const int w = tid >> 6, l = tid & 63;
  const int ntile = blockIdx.x;

  // --- Stage + convert + mask B tile: thread per dst chunk (linear ds_write) ---
  const float* kb = keys + (size_t)ntile * (128 * DIM);
#pragma unroll
  for (int it = 0; it < 8; ++it) {
    int li = it * 256 + tid;
    int rl = ((li >> 8) << 4) + (li & 15);
    int c = (li >> 4) & 15;
    const float* src = kb + rl * DIM + c * 8;
    f32x4 v0 = *(const f32x4*)(src);
    f32x4 v1 = *(const f32x4*)(src + 4);
    int a = act[ntile * 128 + rl];
    short8 o;
    o[0] = (short)f2bf(v0[0]); o[1] = (short)f2bf(v0[1]);
    o[2] = (short)f2bf(v0[2]); o[3] = (short)f2bf(v0[3]);
    o[4] = (short)f2bf(v1[0]); o[5] = (short)f2bf(v1[1]);
    o[6] = (short)f2bf(v1[2]); o[7] = (short)f2bf(v1[3]);
    if (!a) o = short8{0, 0, 0, 0, 0, 0, 0, 0};
    Bs[li] = o;
  }
  __syncthreads();

  const int wr = w >> 1, wc = w & 1;
  const int lg = l >> 4, lr = l & 15;

  // Lift this wave's 16 B fragments into registers (64 VGPR).
  short8 bfv[4][4];  // [ni][kk]
#pragma unroll
  for (int ni = 0; ni < 4; ni++)
#pragma unroll
    for (int kk = 0; kk < 4; kk++)
      bfv[ni][kk] = Bs[(wc * 4 + ni) * 256 + kk * 64 + l];

  const int chunk = ntile * 2 + wc;
  const short8* ag0 = xi + (wr * 4) * 256 + l;

  // --- Barrier-free main loop over 16 x-tiles ---
  for (int bt = 0; bt < 16; ++bt) {
    short8 af[4][4];  // [mi][kk]
#pragma unroll
    for (int mi = 0; mi < 4; mi++)
#pragma unroll
      for (int kk = 0; kk < 4; kk++)
        af[mi][kk] = ag0[(size_t)bt * 2048 + mi * 256 + kk * 64];

    f32x4 acc[4][4];
#pragma unroll
    for (int mi = 0; mi < 4; mi++)
#pragma unroll
      for (int ni = 0; ni < 4; ni++) acc[mi][ni] = f32x4{0.f, 0.f, 0.f, 0.f};

#pragma unroll
    for (int kk = 0; kk < 4; kk++)
#pragma unroll
      for (int mi = 0; mi < 4; mi++)
#pragma unroll
        for (int ni = 0; ni < 4; ni++)
          acc[mi][ni] = __builtin_amdgcn_mfma_f32_16x16x32_bf16(
              af[mi][kk], bfv[ni][kk], acc[mi][ni], 0, 0, 0);

    // Epilogue: per-row max over this wave's 64 key-cols (mask pre-applied).
    // C layout (verified): col = lane&15, row = (lane>>4)*4 + reg.
#pragma unroll
    for (int mi = 0; mi < 4; mi++) {
      float rm[4];
#pragma unroll
      for (int r = 0; r < 4; r++)
        rm[r] = fmaxf(fmaxf(acc[mi][0][r], acc[mi][1][r]),
                      fmaxf(acc[mi][2][r], acc[mi][3][r]));
#pragma unroll
      for (int r = 0; r < 4; r++) {
        float v = rm[r];
        v = fmaxf(v, __shfl_xor(v, 1));
        v = fmaxf(v, __shfl_xor(v, 2));
        v = fmaxf(v, __shfl_xor(v, 4));
        v = fmaxf(v, __shfl_xor(v, 8));
        rm[r] = v;
      }
      if (lr == 0) {
        int row = bt * 128 + wr * 64 + mi * 16 + lg * 4;
#pragma unroll
        for (int r = 0; r < 4; r++)
          cmax[(size_t)(row + r) * 1024 + chunk] = rm[r];
      }
    }
  }
}

// One block per row: reduce 1024 chunk maxima (coalesced row read), fp64-
// rescore candidate chunks (margin 0.75 >> bf16 bound ~0.42 two-sided),
// exact argmax w/ first-index tie-break, write outputs.
__global__ __launch_bounds__(256) void finalize_kernel(
    const float* __restrict__ x, const float* __restrict__ keys,
    const float* __restrict__ vals, const int* __restrict__ act,
    const float* __restrict__ cmax, float* __restrict__ out) {
  __shared__ float xr[128];
  __shared__ float wred[4];
  __shared__ int cand[96];
  __shared__ int ncand;
  __shared__ int bestn_s;
  __shared__ float skeys[64 * 129];  // stride-129 rows -> conflict-free
  const int b = blockIdx.x, tid = threadIdx.x;
  if (tid < 128) xr[tid] = x[(size_t)b * 128 + tid];
  if (tid == 0) ncand = 0;
  __syncthreads();

  const float* cm = cmax + (size_t)b * 1024;
  float c0 = cm[tid], c1 = cm[tid + 256], c2 = cm[tid + 512], c3 = cm[tid + 768];
  float lm = fmaxf(fmaxf(c0, c1), fmaxf(c2, c3));
#pragma unroll
  for (int s = 1; s < 64; s <<= 1) lm = fmaxf(lm, __shfl_xor(lm, s));
  if ((tid & 63) == 0) wred[tid >> 6] = lm;
  __syncthreads();
  float M = fmaxf(fmaxf(wred[0], wred[1]), fmaxf(wred[2], wred[3]));
  float thr = M - 0.75f;

  if (c0 > thr) { int p = atomicAdd(&ncand, 1); if (p < 96) cand[p] = tid; }
  if (c1 > thr) { int p = atomicAdd(&ncand, 1); if (p < 96) cand[p] = tid + 256; }
  if (c2 > thr) { int p = atomicAdd(&ncand, 1); if (p < 96) cand[p] = tid + 512; }
  if (c3 > thr) { int p = atomicAdd(&ncand, 1); if (p < 96) cand[p] = tid + 768; }
  __syncthreads();
  int nc = ncand; if (nc > 96) nc = 96;

  double bv = -(double)__builtin_inf();
  int bn = 0x7FFFFFFF;
  for (int ci = 0; ci < nc; ci++) {
    int cch = cand[ci];
    const float* kbase = keys + (size_t)cch * 64 * 128;
#pragma unroll
    for (int i = 0; i < 32; i++) {
      int idx = tid + i * 256;
      skeys[(idx >> 7) * 129 + (idx & 127)] = kbase[idx];
    }
    __syncthreads();
    if (tid < 64) {
      int n = cch * 64 + tid;
      if (act[n] != 0) {
        const float* kr = skeys + tid * 129;
        double s0 = 0.0, s1 = 0.0, s2 = 0.0, s3 = 0.0;  // 4 indep chains
#pragma unroll
        for (int d = 0; d < 128; d += 4) {
          s0 += (double)xr[d] * (double)kr[d];
          s1 += (double)xr[d + 1] * (double)kr[d + 1];
          s2 += (double)xr[d + 2] * (double)kr[d + 2];
          s3 += (double)xr[d + 3] * (double)kr[d + 3];
        }
        double s = (s0 + s1) + (s2 + s3);
        if (s > bv || (s == bv && n < bn)) { bv = s; bn = n; }
      }
    }
    __syncthreads();
  }

  if (tid < 64) {
#pragma unroll
    for (int s = 1; s < 64; s <<= 1) {
      double ov = __shfl_xor(bv, s);
      int on = __shfl_xor(bn, s);
      if (ov > bv || (ov == bv && on < bn)) { bv = ov; bn = on; }
    }
    if (tid == 0) {
      bestn_s = bn;
      out[262144 + b] = (float)bv;       // confidence
      out[264192 + b] = (float)bn;       // best_match_idx (float-encoded)
    }
  }
  __syncthreads();
  int n = bestn_s;
  if (tid < 128) out[(size_t)b * 128 + tid] = vals[(size_t)n * 128 + tid];
}

// ---------- ws-free fallback (only if ws_size too small): exact fp64 ----------
__global__ __launch_bounds__(256) void direct_kernel(
    const float* __restrict__ x, const float* __restrict__ keys,
    const float* __restrict__ vals, const int* __restrict__ act,
    float* __restrict__ out) {
  __shared__ float xr[8][128];
  __shared__ double redv[8][4];
  __shared__ int redn[8][4];
  __shared__ int bests[8];
  const int tid = threadIdx.x;
  const int r0 = blockIdx.x * 8;
  const int w = tid >> 6, l = tid & 63;
#pragma unroll
  for (int i = 0; i < 4; i++) {
    int idx = tid + i * 256;
    xr[idx >> 7][idx & 127] = x[(size_t)(r0 + (idx >> 7)) * 128 + (idx & 127)];
  }
  __syncthreads();

  double bv[8];
  int bn[8];
#pragma unroll
  for (int r = 0; r < 8; r++) { bv[r] = -(double)__builtin_inf(); bn[r] = 0x7FFFFFFF; }

  for (int n = tid; n < N_KEYS; n += 256) {
    if (act[n] == 0) continue;
    const float* kr = keys + (size_t)n * 128;
    double s[8];
#pragma unroll
    for (int r = 0; r < 8; r++) s[r] = 0.0;
    for (int d = 0; d < 128; d += 4) {
      f32x4 kv = *(const f32x4*)(kr + d);
#pragma unroll
      for (int r = 0; r < 8; r++) {
        s[r] += (double)xr[r][d] * (double)kv[0];
        s[r] += (double)xr[r][d + 1] * (double)kv[1];
        s[r] += (double)xr[r][d + 2] * (double)kv[2];
        s[r] += (double)xr[r][d + 3] * (double)kv[3];
      }
    }
#pragma unroll
    for (int r = 0; r < 8; r++)
      if (s[r] > bv[r]) { bv[r] = s[r]; bn[r] = n; }
  }

#pragma unroll
  for (int r = 0; r < 8; r++) {
    double v = bv[r]; int n = bn[r];
#pragma unroll
    for (int s = 1; s < 64; s <<= 1) {
      double ov = __shfl_xor(v, s);
      int on = __shfl_xor(n, s);
      if (ov > v || (ov == v && on < n)) { v = ov; n = on; }
    }
    if (l == 0) { redv[r][w] = v; redn[r][w] = n; }
  }
  __syncthreads();
  if (tid < 8) {
    double v = redv[tid][0]; int n = redn[tid][0];
#pragma unroll
    for (int j = 1; j < 4; j++) {
      double ov = redv[tid][j]; int on = redn[tid][j];
      if (ov > v || (ov == v && on < n)) { v = ov; n = on; }
    }
    bests[tid] = n;
    out[262144 + r0 + tid] = (float)v;
    out[264192 + r0 + tid] = (float)n;
  }
  __syncthreads();
#pragma unroll
  for (int i = 0; i < 4; i++) {
    int idx = tid + i * 256;
    int r = idx >> 7, d = idx & 127;
    out[(size_t)(r0 + r) * 128 + d] = vals[(size_t)bests[r] * 128 + d];
  }
}

extern "C" void kernel_launch(void* const* d_in, const int* in_sizes, int n_in,
                              void* d_out, int out_size, void* d_ws, size_t ws_size,
                              hipStream_t stream) {
  const float* x    = (const float*)d_in[0];
  const float* keys = (const float*)d_in[1];
  const float* vals = (const float*)d_in[2];
  const int*   act  = (const int*)d_in[3];
  float* out = (float*)d_out;

  const size_t need = (size_t)16 * 2048 * sizeof(short8) +
                      (size_t)B_ROWS * 1024 * sizeof(float);
  if (ws_size >= need) {
    short8* xi   = (short8*)d_ws;
    float*  cmax = (float*)(xi + 16 * 2048);
    convert_x_kernel<<<128, 256, 0, stream>>>(x, xi);
    sim3_kernel<<<512, 256, 0, stream>>>(xi, keys, act, cmax);
    finalize_kernel<<<2048, 256, 0, stream>>>(x, keys, vals, act, cmax, out);
  } else {
    direct_kernel<<<256, 256, 0, stream>>>(x, keys, vals, act, out);
  }
}

// Round 5
// 176.341 us; speedup vs baseline: 1.0781x; 1.0104x over previous
//
#include <hip/hip_runtime.h>
#include <stdint.h>

typedef __attribute__((ext_vector_type(8))) short short8;
typedef __attribute__((ext_vector_type(4))) float f32x4;

#define NEG_INF (-__builtin_inff())

// Problem constants
#define B_ROWS 2048
#define N_KEYS 65536
#define DIM    128
#define NCHUNK 2048   // 32 keys per chunk

// ws layout (fast path):
//   xi:   32768 short8 = 512 KB  (x, bf16, fragment image, linear in rowblk)
//   cmax: 2048 rows * 2048 chunks * 4B = 16 MB  ([row][chunk])

__device__ __forceinline__ unsigned short f2bf(float f) {
  unsigned u = __float_as_uint(f);
  u = (u + 0x7FFFu + ((u >> 16) & 1u)) >> 16;  // RNE
  return (unsigned short)u;
}

// Fragment image (16B chunks), globally linear in 16-row blocks:
//   chunk_idx = (row>>4)*256 + (k/8)*16 + (row&15)
// Lane-l read at (rowblk*256 + kk*64 + l) yields the MFMA 16x16x32 operand
// fragment: index = l&15, k = kk*32 + (l>>4)*8 + e.   [HW-verified r2-r4]
// C layout: col = lane&15, row = (lane>>4)*4 + reg.   [HW-verified r2-r4]

// x f32 -> xi bf16 fragment image. Thread per DST chunk (coalesced writes).
__global__ __launch_bounds__(256) void convert_x_kernel(
    const float* __restrict__ x, short8* __restrict__ xi) {
  int t = blockIdx.x * 256 + threadIdx.x;      // 32768 chunks
  int rb = t >> 8, loc = t & 255;              // rowblk, local
  int rl = rb * 16 + (loc & 15);               // global row
  int c = loc >> 4;                            // k-chunk 0..15
  const float* src = x + (size_t)rl * DIM + c * 8;
  f32x4 v0 = *(const f32x4*)(src);
  f32x4 v1 = *(const f32x4*)(src + 4);
  short8 o;
  o[0] = (short)f2bf(v0[0]); o[1] = (short)f2bf(v0[1]);
  o[2] = (short)f2bf(v0[2]); o[3] = (short)f2bf(v0[3]);
  o[4] = (short)f2bf(v1[0]); o[5] = (short)f2bf(v1[1]);
  o[6] = (short)f2bf(v1[2]); o[7] = (short)f2bf(v1[3]);
  xi[t] = o;
}

// One block (256 thr, 4 waves) per 128-key tile. Keys staged+masked to LDS
// once, each wave lifts ITS 32 keys into 32 VGPRs (swapped A-operand), then
// barrier-free loop over all 64 x-row steps (32 rows each) reading x
// fragments from global xi (L1/L2-resident, shared by all 4 waves).
// Output rows = KEYS, cols = X-ROWS -> key-reduction is in-register + 2 shfl.
__global__ __launch_bounds__(256, 4) void sim4_kernel(
    const short8* __restrict__ xi, const float* __restrict__ keys,
    const int* __restrict__ act, float* __restrict__ cmax) {
  __shared__ short8 Bs[2048];   // 32 KB key image
  const int tid = threadIdx.x;
  const int w = tid >> 6, l = tid & 63;
  const int ntile = blockIdx.x;

  // Stage + convert + mask keys (dst-linear ds_write, conflict-free).
  const float* kb = keys + (size_t)ntile * (128 * DIM);
#pragma unroll
  for (int it = 0; it < 8; ++it) {
    int li = it * 256 + tid;
    int rl = ((li >> 8) << 4) + (li & 15);
    int c = (li >> 4) & 15;
    const float* src = kb + rl * DIM + c * 8;
    f32x4 v0 = *(const f32x4*)(src);
    f32x4 v1 = *(const f32x4*)(src + 4);
    int a = act[ntile * 128 + rl];
    short8 o;
    o[0] = (short)f2bf(v0[0]); o[1] = (short)f2bf(v0[1]);
    o[2] = (short)f2bf(v0[2]); o[3] = (short)f2bf(v0[3]);
    o[4] = (short)f2bf(v1[0]); o[5] = (short)f2bf(v1[1]);
    o[6] = (short)f2bf(v1[2]); o[7] = (short)f2bf(v1[3]);
    if (!a) o = short8{0, 0, 0, 0, 0, 0, 0, 0};
    Bs[li] = o;
  }
  __syncthreads();

  // Lift this wave's 32 keys (2 x 16-key fragments x 4 k-steps) = 32 VGPR.
  short8 kf[2][4];
#pragma unroll
  for (int mi = 0; mi < 2; mi++)
#pragma unroll
    for (int kk = 0; kk < 4; kk++)
      kf[mi][kk] = Bs[(w * 2 + mi) * 256 + kk * 64 + l];

  const int chunk = ntile * 4 + w;           // 32-key chunk id
  const int lr = l & 15;
  float* cbase = cmax + chunk;

  // Barrier-free main loop: 64 steps x 32 x-rows.
  for (int it = 0; it < 64; ++it) {
    short8 xf[2][4];
#pragma unroll
    for (int ni = 0; ni < 2; ni++)
#pragma unroll
      for (int kk = 0; kk < 4; kk++)
        xf[ni][kk] = xi[(it * 2 + ni) * 256 + kk * 64 + l];

    f32x4 acc[2][2];
#pragma unroll
    for (int mi = 0; mi < 2; mi++)
#pragma unroll
      for (int ni = 0; ni < 2; ni++) acc[mi][ni] = f32x4{0.f, 0.f, 0.f, 0.f};

#pragma unroll
    for (int kk = 0; kk < 4; kk++)
#pragma unroll
      for (int mi = 0; mi < 2; mi++)
#pragma unroll
        for (int ni = 0; ni < 2; ni++)
          acc[mi][ni] = __builtin_amdgcn_mfma_f32_16x16x32_bf16(
              kf[mi][kk], xf[ni][kk], acc[mi][ni], 0, 0, 0);

    // Per-x-row max over this wave's 32 keys:
    // key = mi*16 + (l>>4)*4 + r (fold mi,r in-reg; fold l>>4 via 2 shfl),
    // xrow = it*32 + ni*16 + (l&15).
#pragma unroll
    for (int ni = 0; ni < 2; ni++) {
      float t0 = fmaxf(acc[0][ni][0], acc[1][ni][0]);
      float t1 = fmaxf(acc[0][ni][1], acc[1][ni][1]);
      float t2 = fmaxf(acc[0][ni][2], acc[1][ni][2]);
      float t3 = fmaxf(acc[0][ni][3], acc[1][ni][3]);
      float v = fmaxf(fmaxf(t0, t1), fmaxf(t2, t3));
      v = fmaxf(v, __shfl_xor(v, 16));
      v = fmaxf(v, __shfl_xor(v, 32));
      if (l < 16)
        cbase[(size_t)(it * 32 + ni * 16 + lr) * NCHUNK] = v;
    }
  }
}

// One block per row: reduce 2048 chunk maxima (coalesced), fp64-rescore
// candidate 32-key chunks with ALL 256 threads (8 thr/key x 16 dims,
// deterministic butterfly-add), exact argmax w/ first-index tie-break.
// Margin 0.75 >> 2x bf16 one-sided bound ~0.54.
__global__ __launch_bounds__(256) void finalize2_kernel(
    const float* __restrict__ x, const float* __restrict__ keys,
    const float* __restrict__ vals, const int* __restrict__ act,
    const float* __restrict__ cmax, float* __restrict__ out) {
  __shared__ float xr[128];
  __shared__ float wred[4];
  __shared__ int cand[256];
  __shared__ int ncand;
  __shared__ double redv[4];
  __shared__ int redn[4];
  __shared__ int bestn_s;
  const int b = blockIdx.x, tid = threadIdx.x;
  const int w = tid >> 6, l = tid & 63;
  if (tid < 128) xr[tid] = x[(size_t)b * 128 + tid];
  if (tid == 0) ncand = 0;
  __syncthreads();

  const float* cm = cmax + (size_t)b * NCHUNK;
  float c[8];
  float lm = NEG_INF;
#pragma unroll
  for (int j = 0; j < 8; j++) {
    c[j] = cm[tid + j * 256];
    lm = fmaxf(lm, c[j]);
  }
#pragma unroll
  for (int s = 1; s < 64; s <<= 1) lm = fmaxf(lm, __shfl_xor(lm, s));
  if (l == 0) wred[w] = lm;
  __syncthreads();
  float M = fmaxf(fmaxf(wred[0], wred[1]), fmaxf(wred[2], wred[3]));
  float thr = M - 0.75f;

#pragma unroll
  for (int j = 0; j < 8; j++) {
    if (c[j] > thr) {
      int p = atomicAdd(&ncand, 1);
      if (p < 256) cand[p] = tid + j * 256;
    }
  }
  __syncthreads();
  int nc = ncand; if (nc > 256) nc = 256;

  double bv = -(double)__builtin_inf();
  int bn = 0x7FFFFFFF;
  const int key_off = tid >> 3;        // 0..31 within chunk
  const int d0 = (tid & 7) * 16;       // 16-dim slice
  for (int ci = 0; ci < nc; ci++) {
    int n = cand[ci] * 32 + key_off;
    const float* kr = keys + (size_t)n * 128 + d0;
    double s = 0.0;
#pragma unroll
    for (int u = 0; u < 16; u += 4) {
      f32x4 kv = *(const f32x4*)(kr + u);
      s += (double)xr[d0 + u] * (double)kv[0];
      s += (double)xr[d0 + u + 1] * (double)kv[1];
      s += (double)xr[d0 + u + 2] * (double)kv[2];
      s += (double)xr[d0 + u + 3] * (double)kv[3];
    }
    // deterministic 8-lane butterfly sum (same value on all 8 lanes)
    s += __shfl_xor(s, 1);
    s += __shfl_xor(s, 2);
    s += __shfl_xor(s, 4);
    if ((tid & 7) == 0 && act[n] != 0) {
      if (s > bv || (s == bv && n < bn)) { bv = s; bn = n; }
    }
  }

  // Block-wide argmax reduce (inactive lanes hold -inf).
#pragma unroll
  for (int s = 1; s < 64; s <<= 1) {
    double ov = __shfl_xor(bv, s);
    int on = __shfl_xor(bn, s);
    if (ov > bv || (ov == bv && on < bn)) { bv = ov; bn = on; }
  }
  if (l == 0) { redv[w] = bv; redn[w] = bn; }
  __syncthreads();
  if (tid == 0) {
    double v = redv[0]; int n = redn[0];
#pragma unroll
    for (int j = 1; j < 4; j++) {
      if (redv[j] > v || (redv[j] == v && redn[j] < n)) { v = redv[j]; n = redn[j]; }
    }
    bestn_s = n;
    out[262144 + b] = (float)v;        // confidence
    out[264192 + b] = (float)n;        // best_match_idx (float-encoded)
  }
  __syncthreads();
  int n = bestn_s;
  if (tid < 128) out[(size_t)b * 128 + tid] = vals[(size_t)n * 128 + tid];
}

// ---------- ws-free fallback (only if ws_size too small): exact fp64 ----------
__global__ __launch_bounds__(256) void direct_kernel(
    const float* __restrict__ x, const float* __restrict__ keys,
    const float* __restrict__ vals, const int* __restrict__ act,
    float* __restrict__ out) {
  __shared__ float xr[8][128];
  __shared__ double redv[8][4];
  __shared__ int redn[8][4];
  __shared__ int bests[8];
  const int tid = threadIdx.x;
  const int r0 = blockIdx.x * 8;
  const int w = tid >> 6, l = tid & 63;
#pragma unroll
  for (int i = 0; i < 4; i++) {
    int idx = tid + i * 256;
    xr[idx >> 7][idx & 127] = x[(size_t)(r0 + (idx >> 7)) * 128 + (idx & 127)];
  }
  __syncthreads();

  double bv[8];
  int bn[8];
#pragma unroll
  for (int r = 0; r < 8; r++) { bv[r] = -(double)__builtin_inf(); bn[r] = 0x7FFFFFFF; }

  for (int n = tid; n < N_KEYS; n += 256) {
    if (act[n] == 0) continue;
    const float* kr = keys + (size_t)n * 128;
    double s[8];
#pragma unroll
    for (int r = 0; r < 8; r++) s[r] = 0.0;
    for (int d = 0; d < 128; d += 4) {
      f32x4 kv = *(const f32x4*)(kr + d);
#pragma unroll
      for (int r = 0; r < 8; r++) {
        s[r] += (double)xr[r][d] * (double)kv[0];
        s[r] += (double)xr[r][d + 1] * (double)kv[1];
        s[r] += (double)xr[r][d + 2] * (double)kv[2];
        s[r] += (double)xr[r][d + 3] * (double)kv[3];
      }
    }
#pragma unroll
    for (int r = 0; r < 8; r++)
      if (s[r] > bv[r]) { bv[r] = s[r]; bn[r] = n; }
  }

#pragma unroll
  for (int r = 0; r < 8; r++) {
    double v = bv[r]; int n = bn[r];
#pragma unroll
    for (int s = 1; s < 64; s <<= 1) {
      double ov = __shfl_xor(v, s);
      int on = __shfl_xor(n, s);
      if (ov > v || (ov == v && on < n)) { v = ov; n = on; }
    }
    if (l == 0) { redv[r][w] = v; redn[r][w] = n; }
  }
  __syncthreads();
  if (tid < 8) {
    double v = redv[tid][0]; int n = redn[tid][0];
#pragma unroll
    for (int j = 1; j < 4; j++) {
      double ov = redv[tid][j]; int on = redn[tid][j];
      if (ov > v || (ov == v && on < n)) { v = ov; n = on; }
    }
    bests[tid] = n;
    out[262144 + r0 + tid] = (float)v;
    out[264192 + r0 + tid] = (float)n;
  }
  __syncthreads();
#pragma unroll
  for (int i = 0; i < 4; i++) {
    int idx = tid + i * 256;
    int r = idx >> 7, d = idx & 127;
    out[(size_t)(r0 + r) * 128 + d] = vals[(size_t)bests[r] * 128 + d];
  }
}

extern "C" void kernel_launch(void* const* d_in, const int* in_sizes, int n_in,
                              void* d_out, int out_size, void* d_ws, size_t ws_size,
                              hipStream_t stream) {
  const float* x    = (const float*)d_in[0];
  const float* keys = (const float*)d_in[1];
  const float* vals = (const float*)d_in[2];
  const int*   act  = (const int*)d_in[3];
  float* out = (float*)d_out;

  const size_t need = (size_t)32768 * sizeof(short8) +
                      (size_t)B_ROWS * NCHUNK * sizeof(float);
  if (ws_size >= need) {
    short8* xi   = (short8*)d_ws;
    float*  cmax = (float*)(xi + 32768);
    convert_x_kernel<<<128, 256, 0, stream>>>(x, xi);
    sim4_kernel<<<512, 256, 0, stream>>>(xi, keys, act, cmax);
    finalize2_kernel<<<2048, 256, 0, stream>>>(x, keys, vals, act, cmax, out);
  } else {
    direct_kernel<<<256, 256, 0, stream>>>(x, keys, vals, act, out);
  }
}

// Round 9
// 153.451 us; speedup vs baseline: 1.2390x; 1.1492x over previous
//
#include <hip/hip_runtime.h>
#include <stdint.h>

typedef __attribute__((ext_vector_type(8))) short short8;
typedef __attribute__((ext_vector_type(4))) float f32x4;

#define NEG_INF (-__builtin_inff())

// Problem constants
#define B_ROWS 2048
#define N_KEYS 65536
#define DIM    128
#define NCHUNK 1024   // 64 keys per chunk

// ws layout (fast path):
//   xi:   32768 short8  = 512 KB  (x,    bf16 fragment image)
//   ki: 1048576 short8  = 16 MB   (keys, bf16 fragment image, MASKED: inactive=0)
//   cmax: 2048 rows * 1024 chunks * 4B = 8 MB  ([row][chunk])

__device__ __forceinline__ unsigned short f2bf(float f) {
  unsigned u = __float_as_uint(f);
  u = (u + 0x7FFFu + ((u >> 16) & 1u)) >> 16;  // RNE
  return (unsigned short)u;
}

// Fragment image (16B chunks), linear in 16-row blocks:
//   chunk_idx = (row>>4)*256 + (k/8)*16 + (row&15)
// Lane-l read at (rowblk*256 + kk*64 + l) yields the MFMA 16x16x32 operand
// fragment: index = l&15, k = kk*32 + (l>>4)*8 + e.   [HW-verified r2-r5]
// C layout: col = lane&15, row = (lane>>4)*4 + reg.   [HW-verified r2-r5]

// f32 -> bf16 fragment image for BOTH x and keys (keys masked: inactive -> 0).
// Thread per DST chunk -> coalesced writes; scattered reads L2-absorbed.
__global__ __launch_bounds__(256) void convert_kernel(
    const float* __restrict__ x, const float* __restrict__ keys,
    const int* __restrict__ act, short8* __restrict__ xi,
    short8* __restrict__ ki) {
  int t = blockIdx.x * 256 + threadIdx.x;      // 32768 + 1048576 chunks
  const float* src;
  short8* dst;
  int mask = 1;
  if (t < 32768) {
    int rb = t >> 8, loc = t & 255;
    int row = rb * 16 + (loc & 15);
    int c = loc >> 4;
    src = x + (size_t)row * DIM + c * 8;
    dst = xi + t;
  } else {
    t -= 32768;
    int rb = t >> 8, loc = t & 255;
    int row = rb * 16 + (loc & 15);
    int c = loc >> 4;
    src = keys + (size_t)row * DIM + c * 8;
    dst = ki + t;
    mask = act[row];
  }
  f32x4 v0 = *(const f32x4*)(src);
  f32x4 v1 = *(const f32x4*)(src + 4);
  short8 o;
  if (mask) {
    o[0] = (short)f2bf(v0[0]); o[1] = (short)f2bf(v0[1]);
    o[2] = (short)f2bf(v0[2]); o[3] = (short)f2bf(v0[3]);
    o[4] = (short)f2bf(v1[0]); o[5] = (short)f2bf(v1[1]);
    o[6] = (short)f2bf(v1[2]); o[7] = (short)f2bf(v1[3]);
  } else {
    o = short8{0, 0, 0, 0, 0, 0, 0, 0};
  }
  *dst = o;
}

// Grid (256 key-tiles x 4 x-quarters), 4 waves/block, NO LDS.
// Wave w holds 64 keys in registers (kf[4][4], swapped A-operand); loops 32
// iters over its 512-row x-quarter, 16 x-rows/iter. Output rows = KEYS ->
// key-reduction is in-register fold + 2 shfl. Inactive keys pre-zeroed.
__global__ __launch_bounds__(256, 4) void sim5_kernel(
    const short8* __restrict__ xi, const short8* __restrict__ ki,
    float* __restrict__ cmax) {
  const int tid = threadIdx.x;
  const int w = tid >> 6, l = tid & 63;
  const int tile = blockIdx.x;      // 256-key tile
  const int q = blockIdx.y;         // x-quarter (512 rows)

  // Lift this wave's 64 keys: 16 coalesced 16B loads -> 64 VGPR.
  short8 kf[4][4];  // [mi][kk]
#pragma unroll
  for (int mi = 0; mi < 4; mi++) {
    int g = tile * 16 + w * 4 + mi;           // 16-key block
#pragma unroll
    for (int kk = 0; kk < 4; kk++)
      kf[mi][kk] = ki[g * 256 + kk * 64 + l];
  }
  // Pin kf in registers: loads cannot sink past a potential memory writer.
  asm volatile("" ::: "memory");

  const int chunk = tile * 4 + w;   // 64-key chunk id
  const int lr = l & 15;
  const short8* xq = xi + (size_t)q * 8192;   // 512 rows = 32 rowblks * 256

  for (int it = 0; it < 32; ++it) {
    short8 xf[4];
#pragma unroll
    for (int kk = 0; kk < 4; kk++)
      xf[kk] = xq[it * 256 + kk * 64 + l];

    f32x4 acc[4];
#pragma unroll
    for (int mi = 0; mi < 4; mi++) acc[mi] = f32x4{0.f, 0.f, 0.f, 0.f};

#pragma unroll
    for (int kk = 0; kk < 4; kk++)
#pragma unroll
      for (int mi = 0; mi < 4; mi++)
        acc[mi] = __builtin_amdgcn_mfma_f32_16x16x32_bf16(
            kf[mi][kk], xf[kk], acc[mi], 0, 0, 0);

    // Per-x-row max over this wave's 64 keys:
    // key = mi*16 + (l>>4)*4 + r ; xrow = q*512 + it*16 + (l&15).
    float v = acc[0][0];
#pragma unroll
    for (int mi = 0; mi < 4; mi++)
#pragma unroll
      for (int r = 0; r < 4; r++) v = fmaxf(v, acc[mi][r]);
    v = fmaxf(v, __shfl_xor(v, 16));
    v = fmaxf(v, __shfl_xor(v, 32));
    if (l < 16) {
      int row = q * 512 + it * 16 + lr;
      cmax[(size_t)row * NCHUNK + chunk] = v;
    }
  }
}

// One block per row: reduce 1024 chunk maxima (coalesced), fp64-rescore
// candidate 64-key chunks with ALL 256 threads (4 thr/key x 32 dims,
// deterministic butterfly-add), exact argmax w/ first-index tie-break.
// Margin 0.75 >> 2x bf16 one-sided bound ~0.55. No candidate cap (1024 slots).
__global__ __launch_bounds__(256) void finalize3_kernel(
    const float* __restrict__ x, const float* __restrict__ keys,
    const float* __restrict__ vals, const int* __restrict__ act,
    const float* __restrict__ cmax, float* __restrict__ out) {
  __shared__ float xr[128];
  __shared__ float wred[4];
  __shared__ int cand[1024];
  __shared__ int ncand;
  __shared__ double redv[4];
  __shared__ int redn[4];
  __shared__ int bestn_s;
  const int b = blockIdx.x, tid = threadIdx.x;
  const int w = tid >> 6, l = tid & 63;
  if (tid < 128) xr[tid] = x[(size_t)b * 128 + tid];
  if (tid == 0) ncand = 0;
  __syncthreads();

  const float* cm = cmax + (size_t)b * NCHUNK;
  float c[4];
  float lm = NEG_INF;
#pragma unroll
  for (int j = 0; j < 4; j++) {
    c[j] = cm[tid + j * 256];
    lm = fmaxf(lm, c[j]);
  }
#pragma unroll
  for (int s = 1; s < 64; s <<= 1) lm = fmaxf(lm, __shfl_xor(lm, s));
  if (l == 0) wred[w] = lm;
  __syncthreads();
  float M = fmaxf(fmaxf(wred[0], wred[1]), fmaxf(wred[2], wred[3]));
  float thr = M - 0.75f;

#pragma unroll
  for (int j = 0; j < 4; j++) {
    if (c[j] > thr) {
      int p = atomicAdd(&ncand, 1);
      cand[p] = tid + j * 256;
    }
  }
  __syncthreads();
  int nc = ncand;

  double bv = -(double)__builtin_inf();
  int bn = 0x7FFFFFFF;
  const int key_off = tid >> 2;        // 0..63 within chunk
  const int d0 = (tid & 3) * 32;       // 32-dim slice
  for (int ci = 0; ci < nc; ci++) {
    int n = cand[ci] * 64 + key_off;
    const float* kr = keys + (size_t)n * 128 + d0;
    double s = 0.0;
#pragma unroll
    for (int u = 0; u < 32; u += 4) {
      f32x4 kv = *(const f32x4*)(kr + u);
      s += (double)xr[d0 + u] * (double)kv[0];
      s += (double)xr[d0 + u + 1] * (double)kv[1];
      s += (double)xr[d0 + u + 2] * (double)kv[2];
      s += (double)xr[d0 + u + 3] * (double)kv[3];
    }
    // deterministic 4-lane butterfly sum (same value on all 4 lanes)
    s += __shfl_xor(s, 1);
    s += __shfl_xor(s, 2);
    if ((tid & 3) == 0 && act[n] != 0) {
      if (s > bv || (s == bv && n < bn)) { bv = s; bn = n; }
    }
  }

  // Block-wide argmax reduce (inactive lanes hold -inf).
#pragma unroll
  for (int s = 1; s < 64; s <<= 1) {
    double ov = __shfl_xor(bv, s);
    int on = __shfl_xor(bn, s);
    if (ov > bv || (ov == bv && on < bn)) { bv = ov; bn = on; }
  }
  if (l == 0) { redv[w] = bv; redn[w] = bn; }
  __syncthreads();
  if (tid == 0) {
    double v = redv[0]; int n = redn[0];
#pragma unroll
    for (int j = 1; j < 4; j++) {
      if (redv[j] > v || (redv[j] == v && redn[j] < n)) { v = redv[j]; n = redn[j]; }
    }
    bestn_s = n;
    out[262144 + b] = (float)v;        // confidence
    out[264192 + b] = (float)n;        // best_match_idx (float-encoded)
  }
  __syncthreads();
  int n = bestn_s;
  if (tid < 128) out[(size_t)b * 128 + tid] = vals[(size_t)n * 128 + tid];
}

// ---------- ws-free fallback (only if ws_size too small): exact fp64 ----------
__global__ __launch_bounds__(256) void direct_kernel(
    const float* __restrict__ x, const float* __restrict__ keys,
    const float* __restrict__ vals, const int* __restrict__ act,
    float* __restrict__ out) {
  __shared__ float xr[8][128];
  __shared__ double redv[8][4];
  __shared__ int redn[8][4];
  __shared__ int bests[8];
  const int tid = threadIdx.x;
  const int r0 = blockIdx.x * 8;
  const int w = tid >> 6, l = tid & 63;
#pragma unroll
  for (int i = 0; i < 4; i++) {
    int idx = tid + i * 256;
    xr[idx >> 7][idx & 127] = x[(size_t)(r0 + (idx >> 7)) * 128 + (idx & 127)];
  }
  __syncthreads();

  double bv[8];
  int bn[8];
#pragma unroll
  for (int r = 0; r < 8; r++) { bv[r] = -(double)__builtin_inf(); bn[r] = 0x7FFFFFFF; }

  for (int n = tid; n < N_KEYS; n += 256) {
    if (act[n] == 0) continue;
    const float* kr = keys + (size_t)n * 128;
    double s[8];
#pragma unroll
    for (int r = 0; r < 8; r++) s[r] = 0.0;
    for (int d = 0; d < 128; d += 4) {
      f32x4 kv = *(const f32x4*)(kr + d);
#pragma unroll
      for (int r = 0; r < 8; r++) {
        s[r] += (double)xr[r][d] * (double)kv[0];
        s[r] += (double)xr[r][d + 1] * (double)kv[1];
        s[r] += (double)xr[r][d + 2] * (double)kv[2];
        s[r] += (double)xr[r][d + 3] * (double)kv[3];
      }
    }
#pragma unroll
    for (int r = 0; r < 8; r++)
      if (s[r] > bv[r]) { bv[r] = s[r]; bn[r] = n; }
  }

#pragma unroll
  for (int r = 0; r < 8; r++) {
    double v = bv[r]; int n = bn[r];
#pragma unroll
    for (int s = 1; s < 64; s <<= 1) {
      double ov = __shfl_xor(v, s);
      int on = __shfl_xor(n, s);
      if (ov > v || (ov == v && on < n)) { v = ov; n = on; }
    }
    if (l == 0) { redv[r][w] = v; redn[r][w] = n; }
  }
  __syncthreads();
  if (tid < 8) {
    double v = redv[tid][0]; int n = redn[tid][0];
#pragma unroll
    for (int j = 1; j < 4; j++) {
      double ov = redv[tid][j]; int on = redn[tid][j];
      if (ov > v || (ov == v && on < n)) { v = ov; n = on; }
    }
    bests[tid] = n;
    out[262144 + r0 + tid] = (float)v;
    out[264192 + r0 + tid] = (float)n;
  }
  __syncthreads();
#pragma unroll
  for (int i = 0; i < 4; i++) {
    int idx = tid + i * 256;
    int r = idx >> 7, d = idx & 127;
    out[(size_t)(r0 + r) * 128 + d] = vals[(size_t)bests[r] * 128 + d];
  }
}

extern "C" void kernel_launch(void* const* d_in, const int* in_sizes, int n_in,
                              void* d_out, int out_size, void* d_ws, size_t ws_size,
                              hipStream_t stream) {
  const float* x    = (const float*)d_in[0];
  const float* keys = (const float*)d_in[1];
  const float* vals = (const float*)d_in[2];
  const int*   act  = (const int*)d_in[3];
  float* out = (float*)d_out;

  const size_t need = (size_t)(32768 + 1048576) * sizeof(short8) +
                      (size_t)B_ROWS * NCHUNK * sizeof(float);
  if (ws_size >= need) {
    short8* xi   = (short8*)d_ws;
    short8* ki   = xi + 32768;
    float*  cmax = (float*)(ki + 1048576);
    convert_kernel<<<4224, 256, 0, stream>>>(x, keys, act, xi, ki);
    sim5_kernel<<<dim3(256, 4), 256, 0, stream>>>(xi, ki, cmax);
    finalize3_kernel<<<2048, 256, 0, stream>>>(x, keys, vals, act, cmax, out);
  } else {
    direct_kernel<<<256, 256, 0, stream>>>(x, keys, vals, act, out);
  }
}